// Round 5
// baseline (143.408 us; speedup 1.0000x reference)
//
#include <hip/hip_runtime.h>

typedef _Float16 half2 __attribute__((ext_vector_type(2)));
typedef __fp16   fp16x2 __attribute__((ext_vector_type(2)));
typedef _Float16 half4 __attribute__((ext_vector_type(4)));
typedef _Float16 half8 __attribute__((ext_vector_type(8)));
typedef float    f32x4 __attribute__((ext_vector_type(4)));

#define MFMA16(a,b,c) __builtin_amdgcn_mfma_f32_16x16x16f16((a),(b),(c),0,0,0)

static constexpr int N_NODES  = 200000;
static constexpr int N_WIN    = N_NODES / 64;     // 3125 full 64-node windows (exact)

// ---- workspace byte offsets ----
static constexpr size_t WS_ZWT = 0;        // [64][128][16] f16 : (z@W1)^T per graph, d-major k-inner
static constexpr size_t WS_W2T = 262144;   // [128][128] f16    : W2T[d_out][d_in]
static constexpr size_t WS_WHT = 294912;   // [16][128]  f16    : rows 0..3 = [Wp|Wv]^T, rest zero

// ---- LDS layout (37,888 B/block -> 3 blocks/CU with launch_bounds(256,3)) ----
// a2 pairs : [8 mo][4 tp][64 lane] x 16B = 32768
// a3       : [8 mo][64 lane] x 8B       =  4096
// b1,b2    : 128 f32 each               =  1024

// ---------------- prep: W2T + WhT + zW1^T ----------------
__global__ __launch_bounds__(256) void gnn_prep(
    const float* __restrict__ z,
    const float* __restrict__ W1,
    const float* __restrict__ W2,
    const float* __restrict__ Wp,
    const float* __restrict__ Wv,
    _Float16* __restrict__ zwt,
    _Float16* __restrict__ w2t,
    _Float16* __restrict__ wht)
{
    const int b = blockIdx.x, t = threadIdx.x;
    if (b < 64) {
        const int e = b * 256 + t;            // 0..16383
        const int n = e >> 7, kk = e & 127;   // w2t[n][kk] = W2[kk][n]
        w2t[e] = (_Float16)W2[kk * 128 + n];
    } else if (b < 72) {
        const int e = (b - 64) * 256 + t;     // 0..2047
        const int j = e >> 7, d = e & 127;
        float v = 0.f;
        if (j < 2)      v = Wp[d * 2 + j];
        else if (j < 4) v = Wv[d * 2 + (j - 2)];
        wht[e] = (_Float16)v;
    } else {
        const int p = (b - 72) * 2 + (t >> 7);   // 0..1023 = (g,k) pairs
        const int g = p >> 4, k = p & 15, d = t & 127;
        const float* zr = z + (g * 16 + k) * 128;
        float a0 = 0.f, a1 = 0.f, a2 = 0.f, a3 = 0.f;
#pragma unroll 8
        for (int c = 0; c < 128; c += 4) {
            a0 += zr[c    ] * W1[(c    ) * 128 + d];   // W1 coalesced over d
            a1 += zr[c + 1] * W1[(c + 1) * 128 + d];
            a2 += zr[c + 2] * W1[(c + 2) * 128 + d];
            a3 += zr[c + 3] * W1[(c + 3) * 128 + d];
        }
        zwt[(g * 128 + d) * 16 + k] = (_Float16)((a0 + a1) + (a2 + a3));
    }
}

__device__ inline float fast_tanh(float x) {
    x = fminf(fmaxf(x, -15.f), 15.f);
    const float e = __expf(2.f * x);
    return (e - 1.f) / (e + 1.f);
}

__device__ inline half4 cvt4(const f32x4 v) {
    half4 r;
    *(half2*)&r       = __builtin_bit_cast(half2, __builtin_amdgcn_cvt_pkrtz(v[0], v[1]));
    *((half2*)&r + 1) = __builtin_bit_cast(half2, __builtin_amdgcn_cvt_pkrtz(v[2], v[3]));
    return r;
}

__device__ inline half4 relu_cvt4(const f32x4 v) {
    half4 r;
    *(half2*)&r       = __builtin_bit_cast(half2, __builtin_amdgcn_cvt_pkrtz(fmaxf(v[0], 0.f), fmaxf(v[1], 0.f)));
    *((half2*)&r + 1) = __builtin_bit_cast(half2, __builtin_amdgcn_cvt_pkrtz(fmaxf(v[2], 0.f), fmaxf(v[3], 0.f)));
    return r;
}

// ---------------- main: 64-node windows, 4 MFMA group-chains/wave ----------------
__global__ __launch_bounds__(256, 3) void gnn_main(
    const float* __restrict__ s,
    const int* __restrict__ batch,
    const float* __restrict__ b1,
    const float* __restrict__ b2,
    const float* __restrict__ bp,
    const float* __restrict__ bv,
    const _Float16* __restrict__ zwt,
    const _Float16* __restrict__ w2t,
    const _Float16* __restrict__ wht,
    float* __restrict__ out)
{
    __shared__ char lds[37888];
    half8* a2l = (half8*)lds;                 // [mo*4+tp][lane]
    half4* a3l = (half4*)(lds + 32768);       // [mo][lane]
    float* b1l = (float*)(lds + 36864);
    float* b2l = (float*)(lds + 37376);

    const int tid  = threadIdx.x;
    const int lane = tid & 63;
    const int n16  = lane & 15;
    const int quad = lane >> 4;

    // ---- stage weights into LDS ----
#pragma unroll
    for (int r = 0; r < 8; ++r) {
        const int e  = r * 256 + tid;         // 0..2047
        const int mo = e >> 8, tp = (e >> 6) & 3, ll = e & 63;
        const int nn = ll & 15, qq = ll >> 4;
        const _Float16* srcp = w2t + (mo * 16 + nn) * 128 + tp * 32 + qq * 4;
        half8 v;
        *(half4*)&v       = *(const half4*)srcp;        // t = 2tp
        *((half4*)&v + 1) = *(const half4*)(srcp + 16); // t = 2tp+1
        a2l[e] = v;
    }
#pragma unroll
    for (int r = 0; r < 2; ++r) {
        const int ee = r * 256 + tid;         // 0..511 : [mo][lane]
        const int tt = ee >> 6, ll = ee & 63;
        const int nn = ll & 15, qq = ll >> 4;
        a3l[ee] = *(const half4*)(wht + nn * 128 + tt * 16 + qq * 4);
    }
    if (tid < 128)      b1l[tid] = b1[tid];
    else                b2l[tid - 128] = b2[tid - 128];
    __syncthreads();

    f32x4 c3init = {0.f, 0.f, 0.f, 0.f};
    if (quad == 0) { c3init[0] = bp[0]; c3init[1] = bp[1]; c3init[2] = bv[0]; c3init[3] = bv[1]; }

    const int wid = blockIdx.x * 4 + (tid >> 6);
    const int nw  = gridDim.x * 4;            // 3072 waves

    for (int w = wid; w < N_WIN; w += nw) {
        const int base = w * 64;

        // s fragments for 4 groups (independent 16B loads, issued together)
        f32x4 sv[4];
#pragma unroll
        for (int j = 0; j < 4; ++j)
            sv[j] = *(const f32x4*)(s + (base + j * 16 + n16) * 16 + quad * 4);
        const int gLo = batch[base];
        const int gHi = batch[base + 63];

        half4 bs[4];
#pragma unroll
        for (int j = 0; j < 4; ++j) bs[j] = cvt4(sv[j]);

        half4 h1[4][8];                       // 64 VGPR: GEMM1 out = GEMM2 B-frags
        if (gLo == gHi) {
            // fast path (~98%): single graph covers the window
            const _Float16* zg = zwt + gLo * 2048;
#pragma unroll
            for (int mt = 0; mt < 8; ++mt) {
                const half4 a1 = *(const half4*)(zg + (mt * 16 + n16) * 16 + quad * 4);
                const f32x4 cb = *(const f32x4*)(b1l + mt * 16 + quad * 4);
#pragma unroll
                for (int j = 0; j < 4; ++j)
                    h1[j][mt] = relu_cvt4(MFMA16(a1, bs[j], cb));
            }
        } else {
            // boundary window: accumulate GEMM1 over spanning graphs with s masked per node
            int bg[4];
#pragma unroll
            for (int j = 0; j < 4; ++j) bg[j] = batch[base + j * 16 + n16];
            const half4 z4 = {(_Float16)0.f, (_Float16)0.f, (_Float16)0.f, (_Float16)0.f};
#pragma unroll
            for (int mt = 0; mt < 8; ++mt) {
                const f32x4 cb = *(const f32x4*)(b1l + mt * 16 + quad * 4);
                f32x4 acc[4];
#pragma unroll
                for (int j = 0; j < 4; ++j) acc[j] = cb;
                for (int g = gLo; g <= gHi; ++g) {
                    const half4 a1 = *(const half4*)(zwt + (g * 128 + mt * 16 + n16) * 16 + quad * 4);
#pragma unroll
                    for (int j = 0; j < 4; ++j) {
                        const half4 bm = (bg[j] == g) ? bs[j] : z4;
                        acc[j] = MFMA16(a1, bm, acc[j]);
                    }
                }
#pragma unroll
                for (int j = 0; j < 4; ++j) h1[j][mt] = relu_cvt4(acc[j]);
            }
        }

        // GEMM2' + relu + head; each LDS b128 feeds 8 MFMAs, 4 independent chains
        f32x4 acc3[4];
#pragma unroll
        for (int j = 0; j < 4; ++j) acc3[j] = c3init;
#pragma unroll
        for (int mo = 0; mo < 8; ++mo) {
            const f32x4 cb = *(const f32x4*)(b2l + mo * 16 + quad * 4);
            f32x4 acc2[4];
#pragma unroll
            for (int j = 0; j < 4; ++j) acc2[j] = cb;
#pragma unroll
            for (int tp = 0; tp < 4; ++tp) {
                const half8 ww = a2l[(mo * 4 + tp) * 64 + lane];
                const half4 wlo = {ww[0], ww[1], ww[2], ww[3]};
                const half4 whi = {ww[4], ww[5], ww[6], ww[7]};
#pragma unroll
                for (int j = 0; j < 4; ++j) {
                    acc2[j] = MFMA16(wlo, h1[j][tp * 2], acc2[j]);
                    acc2[j] = MFMA16(whi, h1[j][tp * 2 + 1], acc2[j]);
                }
            }
            const half4 w3 = a3l[mo * 64 + lane];
#pragma unroll
            for (int j = 0; j < 4; ++j) {
                const half4 h2 = relu_cvt4(acc2[j]);
                acc3[j] = MFMA16(w3, h2, acc3[j]);
            }
        }

        if (quad == 0) {
#pragma unroll
            for (int j = 0; j < 4; ++j) {
                const int node = base + j * 16 + n16;
                f32x4 o;
                o[0] = fast_tanh(acc3[j][0]);
                o[1] = fast_tanh(acc3[j][1]);
                o[2] = acc3[j][2];
                o[3] = acc3[j][3];
                *(f32x4*)(out + node * 4) = o;
            }
        }
    }
}

extern "C" void kernel_launch(void* const* d_in, const int* in_sizes, int n_in,
                              void* d_out, int out_size, void* d_ws, size_t ws_size,
                              hipStream_t stream)
{
    const float* z     = (const float*)d_in[0];
    const float* s     = (const float*)d_in[1];
    const int*   batch = (const int*)d_in[2];
    const float* W1    = (const float*)d_in[3];
    const float* b1    = (const float*)d_in[4];
    const float* W2    = (const float*)d_in[5];
    const float* b2    = (const float*)d_in[6];
    const float* Wp    = (const float*)d_in[7];
    const float* bp    = (const float*)d_in[8];
    const float* Wv    = (const float*)d_in[9];
    const float* bv    = (const float*)d_in[10];
    float* out = (float*)d_out;

    char* w = (char*)d_ws;
    _Float16* zwt = (_Float16*)(w + WS_ZWT);
    _Float16* w2t = (_Float16*)(w + WS_W2T);
    _Float16* wht = (_Float16*)(w + WS_WHT);

    hipLaunchKernelGGL(gnn_prep, dim3(584), dim3(256), 0, stream,
                       z, W1, W2, Wp, Wv, zwt, w2t, wht);
    hipLaunchKernelGGL(gnn_main, dim3(768), dim3(256), 0, stream,
                       s, batch, b1, b2, bp, bv, zwt, w2t, wht, out);
}